// Round 14
// baseline (163.371 us; speedup 1.0000x reference)
//
#include <hip/hip_runtime.h>
#include <hip/hip_bf16.h>

// FlowNet correlation via bf16 MFMA (gfx950).
// out[b, p*9+o, y, x] = (1/128) sum_c f[b,c,y,x] * s[b,c,y+p-4,x+o-4], zero-pad.
//
// Round 14: PERSISTENT blocks. Cross-round accounting shows a fixed ~12-16us
// cost per BLOCK invariant to shape/traffic/occupancy/pipelining (6 nulls).
// -> 512 blocks x 512 thr, each processing 4 consecutive x-tiles of one
// (b, y-stripe): block lifecycle amortized 4x; tile t+1's chunk-0/1 loads
// issue during tile t's last compute + epilogue. Tile machinery = r11/r13
// (verified): tile (b,4y,16x), 4 k-chunks of 32, dbuf LDS, cvt_pk staging,
// OUT-lds aliases buf0 (WAR barrier before next tile's first stage).

namespace {
constexpr int kC = 128, kH = 128, kW = 256;
constexpr int kWin = 9;
constexpr int kYB = 4, kXB = 16;
constexpr int kSR = kYB + 8;                      // 12 s-rows
constexpr int kSX = kXB + 16;                     // 32 s-cols (x' span)
constexpr int kCP = 40;                           // c-stride (entries), 16B-aligned
constexpr int kKC = 32;                           // channels per chunk
constexpr int kSSz = kSR * kSX * kCP;             // 15360 entries
constexpr int kFSz = kYB * kXB * kCP;             // 2560
constexpr int kBuf = kSSz + kFSz;                 // 17920 entries = 35840 B
constexpr int kSU = kSR * (kSX / 4) * (kKC / 8);  // 384 s staging units
constexpr int kFU = kYB * (kXB / 4) * (kKC / 8);  // 64 f staging units
constexpr int kTU = kSU + kFU;                    // 448 (<= 512, 1/thread)
constexpr int kThreads = 512;                     // 8 waves
constexpr int kTiles = 4;                         // x-tiles per block
constexpr int kBlocks = 4 * (kH / kYB) * (kW / (kXB * kTiles));  // 512
constexpr int kOS = kYB * kXB + 4;                // 68 (x4B=16B-aligned rows)
constexpr int kCStr = kH * kW;                    // 32768

typedef __attribute__((ext_vector_type(8))) short bf16x8;
typedef __attribute__((ext_vector_type(4))) float f32x4;
}  // namespace

__global__ __launch_bounds__(kThreads, 4) void corr_mfma(
    const float* __restrict__ first,
    const float* __restrict__ second,
    float* __restrict__ out)
{
    __shared__ __align__(16) unsigned short lds[2 * kBuf];   // 71.7 KB

    const int tid  = threadIdx.x;
    const int lane = tid & 63;
    const int wid  = tid >> 6;          // 0..7
    const int yslot = wid >> 1;         // 0..3
    const int Ns    = wid & 1;          // N-half 0/1

    // XCD-grouped swizzle: the 4 blocks covering one (b,y-stripe) share an XCD
    // (bid = xcd + 8*seq; same gg -> same xcd), so s-halo re-reads are L2-local.
    const int bid = blockIdx.x;         // 0..511
    const int xcd = bid & 7;
    const int seq = bid >> 3;           // 0..63
    const int xg  = seq & 3;            // which 64-wide x-group
    const int gg  = ((seq >> 2) << 3) + xcd;   // 0..127 = (b, y-stripe)
    const int b   = gg >> 5;
    const int y0  = (gg & 31) * kYB;
    const int X0base = xg * (kXB * kTiles);    // tile t: X0 = X0base + t*16

    const size_t ibase = (size_t)b * kC * kCStr;

    // ---- staging role: tid-invariant LDS slot, per-tile global pointer ----
    int ul = -1;
    if (tid < kSU) {
        int co = tid & 3, xq = (tid >> 2) & 7, row = tid >> 5;
        ul = (row * kSX + xq * 4) * kCP + co * 8;
    } else if (tid < kTU) {
        int u2 = tid - kSU;
        int co = u2 & 3, xq = (u2 >> 2) & 3, row = u2 >> 4;
        ul = kSSz + (row * kXB + xq * 4) * kCP + co * 8;
    }
    auto make_ug = [&](int X0) -> const float* {
        if (tid < kSU) {
            int co = tid & 3, xq = (tid >> 2) & 7, row = tid >> 5;
            int yg = y0 - 4 + row, gx = X0 - 8 + xq * 4;
            if (yg >= 0 && yg < kH && gx >= 0 && gx <= kW - 4)
                return second + ibase + (size_t)(co * 8) * kCStr
                              + (size_t)yg * kW + gx;
            return nullptr;
        } else if (tid < kTU) {
            int u2 = tid - kSU;
            int co = u2 & 3, xq = (u2 >> 2) & 3, row = u2 >> 4;
            return first + ibase + (size_t)(co * 8) * kCStr
                         + (size_t)(y0 + row) * kW + (X0 + xq * 4);
        }
        return nullptr;
    };

    float4 pvA[8], pvB[8];
    auto issue = [&](float4* pv, const float* ug, int kc) {
        if (ul < 0) return;
        const float4 z = make_float4(0.f, 0.f, 0.f, 0.f);
#pragma unroll
        for (int j = 0; j < 8; ++j) pv[j] = z;
        if (ug) {
            const float* gp = ug + (size_t)kc * kKC * kCStr;
#pragma unroll
            for (int j = 0; j < 8; ++j)
                pv[j] = *(const float4*)(gp + (size_t)j * kCStr);
        }
    };
    auto write_lds = [&](int base, const float4* pv) {
        if (ul < 0) return;
#pragma unroll
        for (int xi = 0; xi < 4; ++xi) {
            union { uint4 q; __hip_bfloat162 h[4]; } pk;
#pragma unroll
            for (int jj = 0; jj < 4; ++jj) {
                float lo = ((const float*)&pv[2 * jj])[xi];
                float hi = ((const float*)&pv[2 * jj + 1])[xi];
                pk.h[jj] = __float22bfloat162_rn(make_float2(lo, hi));
            }
            *(uint4*)&lds[base + ul + xi * kCP] = pk.q;
        }
    };

    // ---- compute-side fragment offsets (tile-invariant) ----
    const int l15 = lane & 15, lg = lane >> 4;
    const int aoff = kSSz + (yslot * kXB + l15) * kCP + lg * 8;
    const int boff = (yslot * kSX + Ns * 16 + l15) * kCP + lg * 8;

    f32x4 acc[kWin];
    auto compute = [&](int base) {
        bf16x8 a = *(const bf16x8*)&lds[base + aoff];
#pragma unroll
        for (int p = 0; p < kWin; ++p) {
            bf16x8 bb = *(const bf16x8*)&lds[base + boff + p * (kSX * kCP)];
            acc[p] = __builtin_amdgcn_mfma_f32_16x16x32_bf16(a, bb, acc[p], 0, 0, 0);
        }
    };

    float* outb = (float*)lds;          // OUT aliases buf0 (dead during epilogue)
    const float inv = 1.0f / (float)kC;
    const int delta = Ns ? 12 : -4;
    const size_t ob = (size_t)b * (kWin * kWin) * kCStr;

    // ---- persistent tile loop ----
    const float* ugT = make_ug(X0base);
    issue(pvA, ugT, 0);
    issue(pvB, ugT, 1);

#pragma unroll 1
    for (int t = 0; t < kTiles; ++t) {
        const int X0 = X0base + t * kXB;
        {
            f32x4 z = {0.f, 0.f, 0.f, 0.f};
#pragma unroll
            for (int p = 0; p < kWin; ++p) acc[p] = z;
        }
        // phase 0: fill buf0 (chunk0), issue chunk2
        write_lds(0, pvA);
        issue(pvA, ugT, 2);
        __syncthreads();
        // phase 1: compute c0, stage c1 -> buf1, issue c3
        compute(0);
        write_lds(kBuf, pvB);
        issue(pvB, ugT, 3);
        __syncthreads();
        // phase 2: compute c1, stage c2 -> buf0
        compute(kBuf);
        write_lds(0, pvA);
        __syncthreads();
        // phase 3: compute c2, stage c3 -> buf1; issue next tile's c0/c1
        compute(0);
        write_lds(kBuf, pvB);
        if (t < kTiles - 1) {
            ugT = make_ug(X0 + kXB);
            issue(pvA, ugT, 0);
            issue(pvB, ugT, 1);
        }
        __syncthreads();
        // phase 4: compute c3
        compute(kBuf);
        __syncthreads();

        // ---- epilogue: band-extract into OUT (buf0 alias), then stores ----
#pragma unroll
        for (int p = 0; p < kWin; ++p)
#pragma unroll
            for (int r = 0; r < 4; ++r) {
                int m = (lg << 2) + r;
                int o = l15 - m + delta;
                if (o >= 0 && o < kWin) {
                    int d = p * kWin + o;
                    outb[d * kOS + yslot * kXB + m] = acc[p][r] * inv;
                }
            }
        __syncthreads();
        for (int i = tid; i < kWin * kWin * kYB * (kXB / 4); i += kThreads) {
            int d  = i >> 4;                 // 16 float4 per d (4y x 4xq)
            int r2 = i & 15;
            int yy = r2 >> 2, xq = r2 & 3;
            float4 v = *(const float4*)&outb[d * kOS + yy * kXB + xq * 4];
            *(float4*)&out[ob + ((size_t)d * kH + (y0 + yy)) * kW + X0 + xq * 4] = v;
        }
        __syncthreads();   // WAR: stores read buf0; next tile stages into buf0
    }
}

extern "C" void kernel_launch(void* const* d_in, const int* in_sizes, int n_in,
                              void* d_out, int out_size, void* d_ws, size_t ws_size,
                              hipStream_t stream) {
    const float* first  = (const float*)d_in[0];
    const float* second = (const float*)d_in[1];
    float* out = (float*)d_out;
    dim3 grid(kBlocks);      // 512 persistent blocks (4 tiles each)
    dim3 block(kThreads);    // 512 threads = 8 waves
    hipLaunchKernelGGL(corr_mfma, grid, block, 0, stream, first, second, out);
}

// Round 15
// 65.948 us; speedup vs baseline: 2.4773x; 2.4773x over previous
//
#include <hip/hip_runtime.h>
#include <hip/hip_bf16.h>

// FlowNet correlation via bf16 MFMA (gfx950).
// out[b, p*9+o, y, x] = (1/128) sum_c f[b,c,y,x] * s[b,c,y+p-4,x+o-4], zero-pad.
//
// Round 15 = round 13 (dbuf LDS, dist-2 reg prefetch, tile (b,4y,16x),
// 2048 x 512thr) + COUNTED-VMCNT BARRIERS (T4). __syncthreads makes hipcc
// emit s_waitcnt vmcnt(0) before s_barrier, force-draining the prefetch
// every chunk (m97/m233) -> all prior pipelining was nullified (r12 VGPR=64
// proved loads were sunk). K-loop barriers are now raw
// "s_waitcnt lgkmcnt(0); s_barrier" (LDS ordering only): global loads stay
// in flight across barriers; per-use vmcnt(N) comes from data deps.
// sched_barrier(0) after issue() pins loads early (anti-sink).

namespace {
constexpr int kC = 128, kH = 128, kW = 256;
constexpr int kWin = 9;
constexpr int kYB = 4, kXB = 16;
constexpr int kSR = kYB + 8;                      // 12 s-rows
constexpr int kSX = kXB + 16;                     // 32 s-cols (x' span)
constexpr int kCP = 40;                           // c-stride (entries), 16B-aligned
constexpr int kKC = 32;                           // channels per chunk
constexpr int kSSz = kSR * kSX * kCP;             // 15360 entries
constexpr int kFSz = kYB * kXB * kCP;             // 2560
constexpr int kBuf = kSSz + kFSz;                 // 17920 entries = 35840 B
constexpr int kSU = kSR * (kSX / 4) * (kKC / 8);  // 384 s staging units
constexpr int kFU = kYB * (kXB / 4) * (kKC / 8);  // 64 f staging units
constexpr int kTU = kSU + kFU;                    // 448 (<= 512, 1/thread)
constexpr int kThreads = 512;                     // 8 waves
constexpr int kBlocks = 4 * (kH / kYB) * (kW / kXB);  // 2048
constexpr int kOS = kYB * kXB + 4;                // 68: OUT_lds per-d stride
constexpr int kCStr = kH * kW;                    // 32768

typedef __attribute__((ext_vector_type(8))) short bf16x8;
typedef __attribute__((ext_vector_type(4))) float f32x4;

// Barrier with LDS-only drain: does NOT wait vmcnt -> global prefetch loads
// stay in flight across it (the whole point of this round).
__device__ __forceinline__ void bar_lgkm() {
    asm volatile("s_waitcnt lgkmcnt(0)\n\ts_barrier" ::: "memory");
}
}  // namespace

__global__ __launch_bounds__(kThreads, 4) void corr_mfma(
    const float* __restrict__ first,
    const float* __restrict__ second,
    float* __restrict__ out)
{
    __shared__ __align__(16) unsigned short lds[2 * kBuf];   // 71.7 KB

    const int tid  = threadIdx.x;
    const int lane = tid & 63;
    const int wid  = tid >> 6;          // 0..7
    const int yslot = wid >> 1;         // 0..3
    const int Ns    = wid & 1;          // N-half 0/1

    // XCD-grouped bijective swizzle: 2048 = 8 xcd x 256.
    const int bid = blockIdx.x;
    const int xcd = bid & 7;
    const int seq = bid >> 3;           // 0..255
    const int xt  = seq & 15;
    const int g   = ((seq >> 4) << 3) + xcd;   // 0..127 = (b, y-stripe)
    const int b   = g >> 5;
    const int y0  = (g & 31) * kYB;
    const int X0  = xt * kXB;

    const size_t ibase = (size_t)b * kC * kCStr;

    // ---- staging role: ONE unit per thread (tid < 448) ----
    // unit = (row, x-quad, channel-octet): 8 float4 loads -> 16 cvt_pk -> 4 b128
    const float* ug = nullptr;
    int ul = -1;
    if (tid < kSU) {
        int co = tid & 3, xq = (tid >> 2) & 7, row = tid >> 5;
        int yg = y0 - 4 + row, xg = X0 - 8 + xq * 4;
        ul = (row * kSX + xq * 4) * kCP + co * 8;
        if (yg >= 0 && yg < kH && xg >= 0 && xg <= kW - 4)
            ug = second + ibase + (size_t)(co * 8) * kCStr + (size_t)yg * kW + xg;
    } else if (tid < kTU) {
        int u2 = tid - kSU;
        int co = u2 & 3, xq = (u2 >> 2) & 3, row = u2 >> 4;
        ul = kSSz + (row * kXB + xq * 4) * kCP + co * 8;
        ug = first + ibase + (size_t)(co * 8) * kCStr
                   + (size_t)(y0 + row) * kW + (X0 + xq * 4);
    }

    float4 pvA[8], pvB[8];
    auto issue = [&](float4* pv, int kc) {
        if (ul < 0) return;
        const float4 z = make_float4(0.f, 0.f, 0.f, 0.f);
#pragma unroll
        for (int j = 0; j < 8; ++j) pv[j] = z;
        if (ug) {
            const float* gp = ug + (size_t)kc * kKC * kCStr;
#pragma unroll
            for (int j = 0; j < 8; ++j)
                pv[j] = *(const float4*)(gp + (size_t)j * kCStr);
        }
    };
    auto write_lds = [&](int base, const float4* pv) {
        if (ul < 0) return;
#pragma unroll
        for (int xi = 0; xi < 4; ++xi) {
            union { uint4 q; __hip_bfloat162 h[4]; } pk;
#pragma unroll
            for (int jj = 0; jj < 4; ++jj) {
                float lo = ((const float*)&pv[2 * jj])[xi];
                float hi = ((const float*)&pv[2 * jj + 1])[xi];
                pk.h[jj] = __float22bfloat162_rn(make_float2(lo, hi));
            }
            *(uint4*)&lds[base + ul + xi * kCP] = pk.q;
        }
    };

    // ---- compute-side fragment offsets ----
    const int l15 = lane & 15, lg = lane >> 4;
    const int aoff = kSSz + (yslot * kXB + l15) * kCP + lg * 8;
    const int boff = (yslot * kSX + Ns * 16 + l15) * kCP + lg * 8;

    f32x4 acc[kWin];
    {
        f32x4 z = {0.f, 0.f, 0.f, 0.f};
#pragma unroll
        for (int p = 0; p < kWin; ++p) acc[p] = z;
    }

    auto compute = [&](int base) {
        bf16x8 a = *(const bf16x8*)&lds[base + aoff];
#pragma unroll
        for (int p = 0; p < kWin; ++p) {
            bf16x8 bb = *(const bf16x8*)&lds[base + boff + p * (kSX * kCP)];
            acc[p] = __builtin_amdgcn_mfma_f32_16x16x32_bf16(a, bb, acc[p], 0, 0, 0);
        }
    };

    // ---- pipelined K loop: dbuf LDS, lgkm-only barriers, dist-2 prefetch --
    issue(pvA, 0);
    issue(pvB, 1);
    __builtin_amdgcn_sched_barrier(0);
    write_lds(0, pvA);                  // waits vmcnt for pvA only; pvB in flight
    bar_lgkm();
    // phase 1: issue c2, compute c0, stage c1 -> buf1
    issue(pvA, 2);
    __builtin_amdgcn_sched_barrier(0);
    compute(0);
    write_lds(kBuf, pvB);
    bar_lgkm();
    // phase 2: issue c3, compute c1, stage c2 -> buf0
    issue(pvB, 3);
    __builtin_amdgcn_sched_barrier(0);
    compute(kBuf);
    write_lds(0, pvA);
    bar_lgkm();
    // phase 3: compute c2, stage c3 -> buf1
    compute(0);
    write_lds(kBuf, pvB);
    bar_lgkm();
    // phase 4: compute c3
    compute(kBuf);

    // ---- epilogue: band-extract to OUT_lds (aliases buf0 — last buf0 read
    // fenced by the phase-3 barrier), then coalesced stores ----
    float* outb = (float*)lds;
    const float inv = 1.0f / (float)kC;
    const int delta = Ns ? 12 : -4;
#pragma unroll
    for (int p = 0; p < kWin; ++p)
#pragma unroll
        for (int r = 0; r < 4; ++r) {
            int m = (lg << 2) + r;
            int o = l15 - m + delta;
            if (o >= 0 && o < kWin) {
                int d = p * kWin + o;
                outb[d * kOS + yslot * kXB + m] = acc[p][r] * inv;
            }
        }
    bar_lgkm();

    const size_t ob = (size_t)b * (kWin * kWin) * kCStr;
    for (int i = tid; i < kWin * kWin * kYB * (kXB / 4); i += kThreads) {
        int d  = i >> 4;                 // 16 float4 per d (4y x 4xq)
        int r2 = i & 15;
        int yy = r2 >> 2, xq = r2 & 3;
        float4 v = *(const float4*)&outb[d * kOS + yy * kXB + xq * 4];
        *(float4*)&out[ob + ((size_t)d * kH + (y0 + yy)) * kW + X0 + xq * 4] = v;
    }
}

extern "C" void kernel_launch(void* const* d_in, const int* in_sizes, int n_in,
                              void* d_out, int out_size, void* d_ws, size_t ws_size,
                              hipStream_t stream) {
    const float* first  = (const float*)d_in[0];
    const float* second = (const float*)d_in[1];
    float* out = (float*)d_out;
    dim3 grid(kBlocks);      // 2048 blocks
    dim3 block(kThreads);    // 512 threads = 8 waves
    hipLaunchKernelGGL(corr_mfma, grid, block, 0, stream, first, second, out);
}

// Round 16
// 64.716 us; speedup vs baseline: 2.5244x; 1.0190x over previous
//
#include <hip/hip_runtime.h>
#include <hip/hip_bf16.h>

// FlowNet correlation via bf16 MFMA (gfx950).
// out[b, p*9+o, y, x] = (1/128) sum_c f[b,c,y,x] * s[b,c,y+p-4,x+o-4], zero-pad.
//
// Round 16: COLLAPSE PHASE COUNT. Nulls r10-r15 isolate a fixed ~1.6us cost
// per barrier-phase, invariant to phase content. This kernel runs each block
// in 3 barriers: [stage s(c0..63)+f(all 128c)] -> [compute(c0) || stage s(c64..127)]
// -> [compute(c1)] -> [extract || store].  Tile (b,8y,16x), 1024 blocks x
// 1024 thr (16 waves = 8 yslot x 2 Ns), K-chunk 64, 36 MFMA/wave.
// LDS: s dbuf 2x64KB + f 32KB = 160KB exactly (1 block/CU, 50% occ).
// Bank handling: XOR-swizzle c-octet by (x&7) [s] / (x&15) [f], no pad,
// all b128 16B-aligned, <=2-way aliasing (free, m136).

namespace {
constexpr int kC = 128, kH = 128, kW = 256;
constexpr int kWin = 9;
constexpr int kYB = 8, kXB = 16;
constexpr int kSR = 16, kSX = 32;           // s rows, x' span
constexpr int kKC = 64;                     // channels per chunk (2 chunks)
constexpr int kSBuf = kSR * kSX * kKC;      // 32768 entries = 64 KB
constexpr int kFBase = 2 * kSBuf;           // 65536
constexpr int kFSz = kYB * kXB * kC;        // 16384 entries = 32 KB
constexpr int kLdsE = kFBase + kFSz;        // 81920 entries = 160 KB
constexpr int kThreads = 1024;              // 16 waves
constexpr int kBlocks = 4 * (kH / kYB) * (kW / kXB);  // 1024
constexpr int kOS = kYB * kXB + 4;          // 132: OUT_lds per-d stride
constexpr int kCStr = kH * kW;              // 32768

typedef __attribute__((ext_vector_type(8))) short bf16x8;
typedef __attribute__((ext_vector_type(4))) float f32x4;

__device__ __forceinline__ void bar_lgkm() {
    asm volatile("s_waitcnt lgkmcnt(0)\n\ts_barrier" ::: "memory");
}
}  // namespace

__global__ __launch_bounds__(kThreads, 4) void corr_mfma(
    const float* __restrict__ first,
    const float* __restrict__ second,
    float* __restrict__ out)
{
    __shared__ __align__(16) unsigned short lds[kLdsE];   // 160 KB

    const int tid  = threadIdx.x;
    const int lane = tid & 63;
    const int wid  = tid >> 6;          // 0..15
    const int yslot = wid >> 1;         // 0..7
    const int Ns    = wid & 1;          // N-half 0/1

    // XCD-grouped bijective swizzle: 1024 = 8 xcd x 128; the 16 x-tiles of one
    // (b, y-stripe) share an XCD.
    const int bid = blockIdx.x;
    const int xcd = bid & 7;
    const int seq = bid >> 3;           // 0..127
    const int xt  = seq & 15;
    const int g   = ((seq >> 4) << 3) + xcd;   // 0..63 = (b, y-stripe)
    const int b   = g >> 4;
    const int y0  = (g & 15) * kYB;
    const int X0  = xt * kXB;

    const size_t ibase = (size_t)b * kC * kCStr;

    // ---- s staging unit (ALL 1024 threads): (row, x-quad, c-octet) ----
    const int srow = tid >> 6, srem = tid & 63;
    const int sxq = srem >> 3, sco = srem & 7;
    const int sy = y0 - 4 + srow, sgx = X0 - 8 + sxq * 4;
    const float* sg = nullptr;
    if (sy >= 0 && sy < kH && sgx >= 0 && sgx <= kW - 4)
        sg = second + ibase + (size_t)(sco * 8) * kCStr + (size_t)sy * kW + sgx;
    int sul[4];
#pragma unroll
    for (int xi = 0; xi < 4; ++xi) {
        int x = sxq * 4 + xi;
        sul[xi] = ((srow * kSX + x) << 6) + ((sco ^ (x & 7)) << 3);
    }

    // ---- f staging unit (ALL threads, once): (row, x-quad, c-quad) ----
    const int frow = tid >> 7, frem = tid & 127;
    const int fxq = frem >> 5, fq = frem & 31;
    const float* fg = first + ibase + (size_t)(fq * 4) * kCStr
                            + (size_t)(y0 + frow) * kW + (X0 + fxq * 4);
    int ful[4];
#pragma unroll
    for (int xi = 0; xi < 4; ++xi) {
        int x = fxq * 4 + xi;
        int o = fq >> 1, h = fq & 1;
        ful[xi] = kFBase + ((frow * kXB + x) << 7) + ((o ^ (x & 15)) << 3) + h * 4;
    }

    float4 ps[8], pf[4];
    auto issue_s = [&](int kc) {
        const float4 z = make_float4(0.f, 0.f, 0.f, 0.f);
#pragma unroll
        for (int j = 0; j < 8; ++j) ps[j] = z;
        if (sg) {
            const float* gp = sg + (size_t)kc * kKC * kCStr;
#pragma unroll
            for (int j = 0; j < 8; ++j)
                ps[j] = *(const float4*)(gp + (size_t)j * kCStr);
        }
    };
    auto write_s = [&](int base) {
#pragma unroll
        for (int xi = 0; xi < 4; ++xi) {
            union { uint4 q; __hip_bfloat162 h[4]; } pk;
#pragma unroll
            for (int jj = 0; jj < 4; ++jj) {
                float lo = ((const float*)&ps[2 * jj])[xi];
                float hi = ((const float*)&ps[2 * jj + 1])[xi];
                pk.h[jj] = __float22bfloat162_rn(make_float2(lo, hi));
            }
            *(uint4*)&lds[base + sul[xi]] = pk.q;
        }
    };
    auto issue_f = [&]() {
#pragma unroll
        for (int j = 0; j < 4; ++j)
            pf[j] = *(const float4*)(fg + (size_t)j * kCStr);
    };
    auto write_f = [&]() {
#pragma unroll
        for (int xi = 0; xi < 4; ++xi) {
            union { uint2 q; __hip_bfloat162 h[2]; } pk;
            pk.h[0] = __float22bfloat162_rn(make_float2(
                ((const float*)&pf[0])[xi], ((const float*)&pf[1])[xi]));
            pk.h[1] = __float22bfloat162_rn(make_float2(
                ((const float*)&pf[2])[xi], ((const float*)&pf[3])[xi]));
            *(uint2*)&lds[ful[xi]] = pk.q;
        }
    };

    // ---- compute-side fragment offsets ----
    const int l15 = lane & 15, lg = lane >> 4;
    int afA[2][2];
#pragma unroll
    for (int kc = 0; kc < 2; ++kc)
#pragma unroll
        for (int kk = 0; kk < 2; ++kk)
            afA[kc][kk] = kFBase + ((yslot * kXB + l15) << 7)
                        + (((kc * 8 + kk * 4 + lg) ^ l15) << 3);
    const int sx = Ns * 16 + l15;
    const int o0 = (lg ^ (l15 & 7)) << 3;
    const int o1 = ((4 + lg) ^ (l15 & 7)) << 3;
    const int bbase = (yslot * kSX + sx) << 6;

    f32x4 acc[kWin];
    {
        f32x4 z = {0.f, 0.f, 0.f, 0.f};
#pragma unroll
        for (int p = 0; p < kWin; ++p) acc[p] = z;
    }
    auto compute = [&](int kc) {
        const int sb = kc * kSBuf;
        bf16x8 a0 = *(const bf16x8*)&lds[afA[kc][0]];
        bf16x8 a1 = *(const bf16x8*)&lds[afA[kc][1]];
#pragma unroll
        for (int p = 0; p < kWin; ++p) {
            const int rb = sb + bbase + p * (kSX * kKC);
            bf16x8 b0 = *(const bf16x8*)&lds[rb + o0];
            acc[p] = __builtin_amdgcn_mfma_f32_16x16x32_bf16(a0, b0, acc[p], 0, 0, 0);
            bf16x8 b1 = *(const bf16x8*)&lds[rb + o1];
            acc[p] = __builtin_amdgcn_mfma_f32_16x16x32_bf16(a1, b1, acc[p], 0, 0, 0);
        }
    };

    // ---- 3-barrier schedule ----
    issue_s(0);
    issue_f();
    __builtin_amdgcn_sched_barrier(0);
    write_s(0);            // waits ps(c0) only
    write_f();             // waits pf only
    issue_s(1);            // reuse ps regs; consumed a full phase later
    __builtin_amdgcn_sched_barrier(0);
    bar_lgkm();            // barrier 1: buf0 + f ready
    compute(0);
    write_s(kSBuf);        // stage c1 -> buf1 (overlaps other waves' compute)
    bar_lgkm();            // barrier 2: buf1 ready
    compute(1);
    // no barrier needed: extract writes buf0 region; all buf0 reads were
    // fenced by barrier 2; compute(1) reads only buf1 + f.

    // ---- epilogue: band-extract into OUT (aliases buf0), then stores ----
    float* outb = (float*)lds;
    const float inv = 1.0f / (float)kC;
    const int delta = Ns ? 12 : -4;
#pragma unroll
    for (int p = 0; p < kWin; ++p)
#pragma unroll
        for (int r = 0; r < 4; ++r) {
            int m = (lg << 2) + r;
            int o = l15 - m + delta;
            if (o >= 0 && o < kWin) {
                int d = p * kWin + o;
                outb[d * kOS + yslot * kXB + m] = acc[p][r] * inv;
            }
        }
    bar_lgkm();            // barrier 3: OUT complete

    const size_t ob = (size_t)b * (kWin * kWin) * kCStr;
    for (int i = tid; i < kWin * kWin * kYB * (kXB / 4); i += kThreads) {
        int d  = i >> 5;                 // 32 float4 per d (8y x 4xq)
        int r2 = i & 31;
        int yy = r2 >> 2, xq = r2 & 3;
        float4 v = *(const float4*)&outb[d * kOS + yy * kXB + xq * 4];
        *(float4*)&out[ob + ((size_t)d * kH + (y0 + yy)) * kW + X0 + xq * 4] = v;
    }
}

extern "C" void kernel_launch(void* const* d_in, const int* in_sizes, int n_in,
                              void* d_out, int out_size, void* d_ws, size_t ws_size,
                              hipStream_t stream) {
    const float* first  = (const float*)d_in[0];
    const float* second = (const float*)d_in[1];
    float* out = (float*)d_out;
    dim3 grid(kBlocks);      // 1024 blocks
    dim3 block(kThreads);    // 1024 threads = 16 waves
    hipLaunchKernelGGL(corr_mfma, grid, block, 0, stream, first, second, out);
}